// Round 8
// baseline (151.001 us; speedup 1.0000x reference)
//
#include <hip/hip_runtime.h>
#include <cmath>

#define NKEY 3072
#define KSEL 100
#define PCHUNK 200   // preds per maxiou tile; 6400/200 = 32 chunks x 25 target groups = 800 tiles
#define NBLK 256

static __device__ __forceinline__ float sigf(float v) {
    return 1.0f / (1.0f + expf(-v));
}

// Block (256 threads) sum-reduction in double. Valid result on thread 0.
// Leading barrier makes back-to-back calls safe.
static __device__ double block_reduce_sum(double v) {
    __shared__ double sh[4];
    __syncthreads();
    for (int off = 32; off > 0; off >>= 1) v += __shfl_down(v, off, 64);
    int lane = threadIdx.x & 63, wid = threadIdx.x >> 6;
    if (lane == 0) sh[wid] = v;
    __syncthreads();
    v = (threadIdx.x < 4) ? sh[threadIdx.x] : 0.0;
    if (wid == 0) {
        v += __shfl_down(v, 2, 64);
        v += __shfl_down(v, 1, 64);
    }
    return v;
}

// Grid-wide barrier: monotone arrival counter (zeroed by hipMemsetAsync before
// launch). All 256 blocks (256 thr, ~35 KB LDS) are co-resident on 256 CUs, so
// spinning is deadlock-free. atomicAdd(,0) = device-coherent read; threadfence
// before arrive = release, after wait = acquire (covers per-XCD L2s).
static __device__ void gsync(unsigned int* bar, unsigned int target) {
    __syncthreads();
    if (threadIdx.x == 0) {
        __threadfence();
        atomicAdd(bar, 1u);
        while (atomicAdd(bar, 0u) < target) __builtin_amdgcn_s_sleep(8);
        __threadfence();
    }
    __syncthreads();
}

// ---------------------------------------------------------------------------
// Single fused kernel, 256 blocks x 256 threads:
//  phase 1 (blocks 0..63): per-batch radix-select top-100 (jax.lax.top_k
//           semantics), negpen partial, target fixing, paired DIoU + SL1
//  phase 2 (all blocks): 800 max-IoU tiles, strided; atomicMax per target
//  phase 3 (all blocks): 625 pair-broadcast tiles, strided; last block
//           finalizes the scalar output
// ---------------------------------------------------------------------------
__global__ __launch_bounds__(256) void k_fused(
        const float* __restrict__ pred, const float* __restrict__ tgt,
        float* __restrict__ predc, float* __restrict__ targc,
        float* __restrict__ confv, unsigned int* __restrict__ maxiou_bits,
        double* __restrict__ negp /*[64]*/, float* __restrict__ diouv,
        double* __restrict__ sl1p /*[64]*/, unsigned int* __restrict__ bar,
        double* __restrict__ pair_sum, unsigned int* __restrict__ done_cnt,
        float* __restrict__ out) {
    const int bid = blockIdx.x;
    const int t = threadIdx.x;

    __shared__ unsigned long long keys[NKEY];   // 24 KB (phase 1)
    __shared__ unsigned int hist[256];
    __shared__ unsigned long long sel[KSEL];
    __shared__ float4 pbox[KSEL];
    __shared__ float4 tbox[KSEL];
    __shared__ unsigned long long tkey_sh;
    __shared__ unsigned int scnt;
    __shared__ int bdigit_sh;
    __shared__ int bk_sh;
    __shared__ float4 pl[PCHUNK];               // phase 2
    __shared__ float pa_sh[PCHUNK];
    __shared__ float oy2s[256];                 // phase 3
    __shared__ float sl1_sh;

    // ================= phase 1: per-batch top-k (blocks 0..63) =============
    if (bid < 64) {
        const int b = bid;

        // target box fixing (epsilon = 1.0) + maxiou init
        if (t < KSEL) {
            int n = b * KSEL + t;
            const float* tb = tgt + (size_t)n * 4;
            float a0 = tb[0], a1 = tb[1], a2 = tb[2], a3 = tb[3];
            float x1 = fminf(a0, a2), y1 = fminf(a1, a3);
            float x2 = fmaxf(a0, a2), y2 = fmaxf(a1, a3);
            if (x1 == x2) x2 = x1 + 1.0f;
            if (y1 == y2) y2 = y1 + 1.0f;
            targc[n * 4 + 0] = x1; targc[n * 4 + 1] = y1;
            targc[n * 4 + 2] = x2; targc[n * 4 + 3] = y2;
            tbox[t] = make_float4(x1, y1, x2, y2);
            maxiou_bits[n] = 0u;
        }
        if (t == 0) scnt = 0;

        // phase A: keys (conf_bits<<32 | ~idx; conf>0 => monotone) + negpen
        const float* pb = pred + (size_t)b * (NKEY * 5);
        float negacc = 0.0f;
        for (int r = 0; r < 12; ++r) {
            int idx = t + r * 256;
            const float* pe = pb + (size_t)idx * 5;
            float w = pe[2], h = pe[3], cl = pe[4];
            negacc += fmaxf(1.0f - w, 0.0f) + fmaxf(1.0f - h, 0.0f);
            float c = sigf(cl);
            keys[idx] = ((unsigned long long)__float_as_uint(c) << 32)
                      | (unsigned long long)(0xFFFFFFFFu - (unsigned)idx);
        }
        {
            double v = block_reduce_sum((double)negacc);
            if (t == 0) negp[b] = v;
        }
        __syncthreads();  // keys + scnt + tbox visible

        // phase B: radix select the exact 100th-largest key (MSB-first)
        unsigned long long prefix = 0ull;
        int plen = 0;
        int k = KSEL;
        bool done = false;
        for (int round = 0; round < 8 && !done; ++round) {
            hist[t] = 0u;
            __syncthreads();
            int shift = 56 - 8 * round;
            for (int r = 0; r < 12; ++r) {
                unsigned long long key = keys[t + r * 256];
                if (plen == 0 || (key >> (64 - plen)) == (prefix >> (64 - plen))) {
                    atomicAdd(&hist[(unsigned)((key >> shift) & 0xFFull)], 1u);
                }
            }
            __syncthreads();
            if (t < 64) {  // wave 0: suffix-scan the 256-bin histogram
                unsigned s0 = hist[4 * t + 0], s1 = hist[4 * t + 1];
                unsigned s2 = hist[4 * t + 2], s3 = hist[4 * t + 3];
                unsigned ssum = s0 + s1 + s2 + s3;
                unsigned suf = ssum;
                for (int off = 1; off < 64; off <<= 1) {
                    unsigned o = __shfl_down(suf, off, 64);
                    if (t + off < 64) suf += o;
                }
                unsigned above = suf - ssum;
                if (above < (unsigned)k && suf >= (unsigned)k) {
                    unsigned hh[4] = {s0, s1, s2, s3};
                    unsigned cum = above;
                    for (int q = 3; q >= 0; --q) {
                        unsigned c = hh[q];
                        if (cum + c >= (unsigned)k) { bdigit_sh = 4 * t + q; bk_sh = k - (int)cum; break; }
                        cum += c;
                    }
                }
            }
            __syncthreads();
            int d = bdigit_sh;
            k = bk_sh;
            prefix |= ((unsigned long long)(unsigned)d) << shift;
            plen += 8;
            unsigned ceq = hist[d];
            if (ceq == 1u) {
                for (int r = 0; r < 12; ++r) {
                    unsigned long long key = keys[t + r * 256];
                    if ((key >> (64 - plen)) == (prefix >> (64 - plen))) tkey_sh = key;
                }
                done = true;
            }
            __syncthreads();
        }
        unsigned long long T = tkey_sh;

        // phase C: compact + rank + emit
        for (int r = 0; r < 12; ++r) {
            unsigned long long key = keys[t + r * 256];
            if (key >= T) {
                unsigned pos = atomicAdd(&scnt, 1u);  // exactly 100 total
                sel[pos] = key;
            }
        }
        __syncthreads();
        if (t < KSEL) {
            unsigned long long key = sel[t];
            int rank = 0;
            for (int p = 0; p < KSEL; ++p) rank += (sel[p] > key) ? 1 : 0;
            unsigned idx = 0xFFFFFFFFu - (unsigned)(key & 0xFFFFFFFFull);
            float conf = __uint_as_float((unsigned)(key >> 32));
            int n = b * KSEL + rank;
            confv[n] = conf;
            const float* pe = pb + (size_t)idx * 5;
            int w = idx & 31, h = (idx >> 5) & 31;  // flat = a*1024 + h*32 + w
            float x  = (sigf(pe[0]) + (float)w) * 32.0f;
            float y  = (sigf(pe[1]) + (float)h) * 32.0f;
            float bw = expf(pe[2]) * 32.0f;
            float bh = expf(pe[3]) * 32.0f;
            float4 pc = make_float4(x - bw * 0.5f, y - bh * 0.5f,
                                    x + bw * 0.5f, y + bh * 0.5f);
            predc[n * 4 + 0] = pc.x; predc[n * 4 + 1] = pc.y;
            predc[n * 4 + 2] = pc.z; predc[n * 4 + 3] = pc.w;
            pbox[rank] = pc;
        }
        __syncthreads();

        // phase D: paired DIoU + smooth-L1 partial (pairing n<->n, from LDS)
        double s = 0.0;
        if (t < KSEL) {
            float4 p = pbox[t];
            float4 tj = tbox[t];
            float pa = fmaxf(p.z - p.x, 0.f) * fmaxf(p.w - p.y, 0.f);
            float ta2 = fmaxf(tj.z - tj.x, 0.f) * fmaxf(tj.w - tj.y, 0.f);
            float ix1 = fmaxf(p.x, tj.x), iy1 = fmaxf(p.y, tj.y);
            float ix2 = fminf(p.z, tj.z), iy2 = fminf(p.w, tj.w);
            float inter = fmaxf(ix2 - ix1, 0.f) * fmaxf(iy2 - iy1, 0.f);
            float iou = inter / (pa + ta2 - inter + 1e-7f);
            float pcx = (p.x + p.z) * 0.5f, pcy = (p.y + p.w) * 0.5f;
            float tcx = (tj.x + tj.z) * 0.5f, tcy = (tj.y + tj.w) * 0.5f;
            float cd = (pcx - tcx) * (pcx - tcx) + (pcy - tcy) * (pcy - tcy);
            float ex1 = fminf(p.x, tj.x), ey1 = fminf(p.y, tj.y);
            float ex2 = fmaxf(p.z, tj.z), ey2 = fmaxf(p.w, tj.w);
            float dg = (ex2 - ex1) * (ex2 - ex1) + (ey2 - ey1) * (ey2 - ey1);
            diouv[b * KSEL + t] = 1.0f - (iou - cd / (dg + 1e-7f));
            float d0 = p.x - tj.x, d1 = p.y - tj.y, d2 = p.z - tj.z, d3 = p.w - tj.w;
            float a0 = fabsf(d0), a1 = fabsf(d1), a2 = fabsf(d2), a3 = fabsf(d3);
            s += (double)(a0 < 1.f ? 0.5f * d0 * d0 : a0 - 0.5f);
            s += (double)(a1 < 1.f ? 0.5f * d1 * d1 : a1 - 0.5f);
            s += (double)(a2 < 1.f ? 0.5f * d2 * d2 : a2 - 0.5f);
            s += (double)(a3 < 1.f ? 0.5f * d3 * d3 : a3 - 0.5f);
        }
        double v = block_reduce_sum(s);
        if (t == 0) sl1p[b] = v;
    }

    gsync(bar, NBLK);  // barrier 1: topk outputs visible device-wide

    // ================= phase 2: global max-IoU (800 tiles, strided) ========
    const float4* pc4 = (const float4*)predc;
    const float4* tc4 = (const float4*)targc;
    for (int tile = bid; tile < 800; tile += NBLK) {
        int tx = tile >> 5;        // target group 0..24
        int ty = tile & 31;        // pred chunk 0..31
        int j = tx * 256 + t;
        int i0 = ty * PCHUNK;
        if (t < PCHUNK) {
            float4 p = pc4[i0 + t];
            pl[t] = p;
            pa_sh[t] = (p.z - p.x) * (p.w - p.y);
        }
        float4 tj = tc4[j];
        float ta = (tj.z - tj.x) * (tj.w - tj.y);
        __syncthreads();
        float m0 = 0.0f, m1 = 0.0f;
        #pragma unroll 2
        for (int i = 0; i < PCHUNK; i += 2) {
            float4 p = pl[i];
            float w0 = fmaxf(fminf(p.z, tj.z) - fmaxf(p.x, tj.x), 0.0f);
            float h0 = fmaxf(fminf(p.w, tj.w) - fmaxf(p.y, tj.y), 0.0f);
            float in0 = w0 * h0;
            float iou0 = in0 * __builtin_amdgcn_rcpf(pa_sh[i] + ta - in0);  // union > 0
            m0 = fmaxf(m0, iou0);
            float4 q = pl[i + 1];
            float w1 = fmaxf(fminf(q.z, tj.z) - fmaxf(q.x, tj.x), 0.0f);
            float h1 = fmaxf(fminf(q.w, tj.w) - fmaxf(q.y, tj.y), 0.0f);
            float in1 = w1 * h1;
            float iou1 = in1 * __builtin_amdgcn_rcpf(pa_sh[i + 1] + ta - in1);
            m1 = fmaxf(m1, iou1);
        }
        m0 = fmaxf(m0, m1);
        atomicMax(&maxiou_bits[j], __float_as_uint(m0));  // IoU >= 0: bit-compare ok
        __syncthreads();  // protect pl reuse next tile
    }

    gsync(bar, 2 * NBLK);  // barrier 2: maxiou complete

    // ================= phase 3: pair-broadcast sum (625 tiles, strided) ====
    if (t == 0) {
        double s = 0.0;
        for (int i = 0; i < 64; ++i) s += sl1p[i];
        sl1_sh = (float)(s / 25600.0 / 512.0);
    }
    double accd = 0.0;
    for (int tile = bid; tile < 625; tile += NBLK) {
        int tx = tile / 25;        // x (target) group 0..24
        int ty = tile - tx * 25;   // y (conf) group 0..24
        {
            float oy = 1.0f - confv[ty * 256 + t];
            oy2s[t] = oy * oy;
        }
        int j = tx * 256 + t;
        float mj = __uint_as_float(maxiou_bits[j]);
        float dj = diouv[j];
        __syncthreads();           // publishes oy2s + sl1_sh
        float xj = (1.0f - mj) * 2.0f + dj + sl1_sh;
        float a2 = xj * xj;
        float bb = 3.5f - xj;
        float b2 = bb * bb;
        float acc0 = 0.0f, acc1 = 0.0f;
        #pragma unroll 4
        for (int i = 0; i < 256; i += 2) {
            float o0 = oy2s[i], o1 = oy2s[i + 1];
            acc0 += 2.0f * __builtin_amdgcn_sqrtf(a2 + o0)
                  - 1.5f * __builtin_amdgcn_sqrtf(b2 + o0);
            acc1 += 2.0f * __builtin_amdgcn_sqrtf(a2 + o1)
                  - 1.5f * __builtin_amdgcn_sqrtf(b2 + o1);
        }
        accd += (double)(acc0 + acc1);
        __syncthreads();           // protect oy2s reuse next tile
    }
    double v = block_reduce_sum(accd);
    if (t == 0) {
        atomicAdd(pair_sum, v);
        __threadfence();
        unsigned prev = atomicAdd(done_cnt, 1u);
        if (prev == NBLK - 1u) {   // last block: finalize
            __threadfence();
            double ps = atomicAdd(pair_sum, 0.0);  // coherent read
            double ns = 0.0;
            for (int i = 0; i < 64; ++i) ns += negp[i];
            double mean_pair = ps / 40960000.0;                    // 6400*6400
            float losses = fmaxf((float)mean_pair + 5.25f, 0.0f);  // + 3.5*1.5
            float neg = (float)(ns / 196608.0);
            out[0] = losses + neg;
        }
    }
}

// ---------------- launch ----------------

extern "C" void kernel_launch(void* const* d_in, const int* in_sizes, int n_in,
                              void* d_out, int out_size, void* d_ws, size_t ws_size,
                              hipStream_t stream) {
    const float* pred = (const float*)d_in[0];   // [64,3,32,32,5]
    const float* tgt  = (const float*)d_in[1];   // [64,100,4]
    float* out = (float*)d_out;

    char* ws = (char*)d_ws;
    unsigned int* bar      = (unsigned int*)(ws + 0);    // 4 B
    double* pair_sum       = (double*)(ws + 8);          // 8 B
    unsigned int* done_cnt = (unsigned int*)(ws + 16);   // 4 B
    double* negp  = (double*)(ws + 64);      // 64 doubles
    double* sl1p  = (double*)(ws + 576);     // 64 doubles
    float* fbase  = (float*)(ws + 6400);     // 16B-aligned float region
    float* predc  = fbase;                   // 25600 floats
    float* targc  = fbase + 25600;           // 25600
    float* confv  = fbase + 51200;           // 6400
    float* diouv  = fbase + 57600;           // 6400
    unsigned int* maxiou_bits = (unsigned int*)(fbase + 64000);  // 6400

    hipMemsetAsync(ws, 0, 64, stream);       // zero bar / pair_sum / done_cnt
    k_fused<<<NBLK, 256, 0, stream>>>(pred, tgt, predc, targc, confv, maxiou_bits,
                                      negp, diouv, sl1p, bar, pair_sum, done_cnt, out);
}